// Round 7
// baseline (130.364 us; speedup 1.0000x reference)
//
#include <hip/hip_runtime.h>

#define C 128   // channels = nh*d = 8*16

// wave-local LDS fence: all attn LDS buffers are per-wave.
__device__ __forceinline__ void wave_sync() {
  __builtin_amdgcn_wave_barrier();
  asm volatile("s_waitcnt lgkmcnt(0)" ::: "memory");
  __builtin_amdgcn_wave_barrier();
}

// transpose one 64x64 tile of [b, C, P] -> head-major [b, h, P, 16]
__device__ __forceinline__ void transpose_tile(const float* __restrict__ in,
                                               float* __restrict__ out, int P,
                                               int tx, int chHalf, int b,
                                               float (*tile)[65]) {
  int posBase = tx * 64;
  int chBase  = chHalf * 64;
  int tid = threadIdx.x;
  int lp = tid & 63;
  int lr = tid >> 6;
  const float* ip = in + (size_t)b * C * P;
  float* op = out + (size_t)b * C * P;
#pragma unroll
  for (int it = 0; it < 16; ++it) {
    int ch = lr + it * 4;
    tile[ch][lp] = ip[(size_t)(chBase + ch) * P + posBase + lp];
  }
  __syncthreads();
  int ch2 = chBase + lp;
  int hh = ch2 >> 4, dd = ch2 & 15;
#pragma unroll
  for (int it = 0; it < 16; ++it) {
    int pl = lr + it * 4;
    op[((size_t)hh * P + posBase + pl) * 16 + dd] = tile[lp][pl];
  }
}

// ---------------- K1: coarse transpose (768 blocks) ----------------
__global__ __launch_bounds__(256) void transpose_coarse(
    const float* __restrict__ q, const float* __restrict__ k,
    const float* __restrict__ v, float* __restrict__ qo,
    float* __restrict__ ko, float* __restrict__ vo) {
  __shared__ alignas(16) float tile[64][65];
  int idx = blockIdx.x;
  int tx = idx & 63;
  int ty = (idx >> 6) % 6;
  int tz = idx / 384;
  int sel = ty >> 1;
  const float* in = sel == 0 ? q : sel == 1 ? k : v;
  float* out      = sel == 0 ? qo : sel == 1 ? ko : vo;
  transpose_tile(in, out, 4096, tx, ty & 1, tz, tile);
}

// ---------------- K3: fine transpose (3072 blocks, pure streaming) --------
__global__ __launch_bounds__(256) void transpose_fine(
    const float* __restrict__ q, const float* __restrict__ k,
    const float* __restrict__ v, float* __restrict__ qo,
    float* __restrict__ ko, float* __restrict__ vo) {
  __shared__ alignas(16) float tile[64][65];
  int idx = blockIdx.x;
  int tx = idx & 255;
  int ty = (idx >> 8) % 6;
  int tz = idx / 1536;
  int sel = ty >> 1;
  const float* in = sel == 0 ? q : sel == 1 ? k : v;
  float* out      = sel == 0 ? qo : sel == 1 ? ko : vo;
  transpose_tile(in, out, 16384, tx, ty & 1, tz, tile);
}

// ---------------- K2: coarse attention, 2 units per wave ----------------
// Exact per-unit softmax + stable rank path (identical numerics to the
// validated single-unit version), two independent units (adjacent coarse
// columns, same head) interleaved per wave for latency hiding.
__global__ __launch_bounds__(256) void attn_coarse2(
    const float* __restrict__ qt, const float* __restrict__ kt,
    const float* __restrict__ vt, const int* __restrict__ parents,
    float* __restrict__ mc, int* __restrict__ ti_out)
{
  __shared__ alignas(16) float als_t[4][2][4][64];    // [wave][u][t][k]
  __shared__ alignas(16) float als_k[4][2][4][17][4]; // [wave][u][g][kk][t]
  __shared__ alignas(16) float qls[4][2][4][16];
  __shared__ alignas(16) int   cofs[4][2][64];

  const int lane = threadIdx.x & 63;
  const int wid  = threadIdx.x >> 6;
  const int wg = (blockIdx.x & 7) * 256 + (blockIdx.x >> 3); // XCD swizzle
  const int p  = wg * 4 + wid;        // pair id [0, 8192)
  const int wb2 = p & 15;
  const int hb  = (p >> 4) & 31;
  const int h   = (p >> 9) & 7;
  const int b   = p >> 12;
  const int bh  = b * 8 + h;
  const int hD  = h * 16;
  const int wbA = wb2 * 2, wbB = wbA + 1;
  const int nA  = hb * 32 + wbA;      // unit B = nA + 1

  // q loads (both units)
  { int t = lane >> 4, dd = lane & 15;
    int row = (hb * 2 + (t >> 1)) * 64;
    int colA = wbA * 2 + (t & 1);
    qls[wid][0][t][dd] = qt[((size_t)bh * 4096 + row + colA    ) * 16 + dd];
    qls[wid][1][t][dd] = qt[((size_t)bh * 4096 + row + colA + 2) * 16 + dd];
  }
  // parents -> candidate positions + element offsets
  int candA, candB, offA, offB;
  { int kp = lane >> 2, c = lane & 3;
    size_t baseR = (size_t)b * 131072 + kp * 8 + h;
    int rA = parents[baseR           + (size_t)nA * 128];
    int cA = parents[baseR + 262144  + (size_t)nA * 128];
    int rB = parents[baseR           + (size_t)(nA + 1) * 128];
    int cB = parents[baseR + 262144  + (size_t)(nA + 1) * 128];
    candA = (2 * rA + (c >> 1)) * 64 + 2 * cA + (c & 1);
    candB = (2 * rB + (c >> 1)) * 64 + 2 * cB + (c & 1);
    offA = (bh * 4096 + candA) * 16;
    offB = (bh * 4096 + candB) * 16;
    cofs[wid][0][lane] = offA;
    cofs[wid][1][lane] = offB;
  }
  wave_sync();

  // K gathers (two independent 64B rows in flight)
  float4 kA0, kA1, kA2, kA3, kB0, kB1, kB2, kB3;
  { const float4* kv = (const float4*)(kt + offA); kA0 = kv[0]; kA1 = kv[1]; kA2 = kv[2]; kA3 = kv[3]; }
  { const float4* kv = (const float4*)(kt + offB); kB0 = kv[0]; kB1 = kv[1]; kB2 = kv[2]; kB3 = kv[3]; }

  float scA[4], scB[4];
#pragma unroll
  for (int t = 0; t < 4; ++t) {
    { const float4* qv = (const float4*)qls[wid][0][t];
      float4 q0 = qv[0], q1 = qv[1], q2 = qv[2], q3 = qv[3];
      float acc = kA0.x*q0.x + kA0.y*q0.y + kA0.z*q0.z + kA0.w*q0.w
                + kA1.x*q1.x + kA1.y*q1.y + kA1.z*q1.z + kA1.w*q1.w
                + kA2.x*q2.x + kA2.y*q2.y + kA2.z*q2.z + kA2.w*q2.w
                + kA3.x*q3.x + kA3.y*q3.y + kA3.z*q3.z + kA3.w*q3.w;
      scA[t] = acc * 0.25f; }
    { const float4* qv = (const float4*)qls[wid][1][t];
      float4 q0 = qv[0], q1 = qv[1], q2 = qv[2], q3 = qv[3];
      float acc = kB0.x*q0.x + kB0.y*q0.y + kB0.z*q0.z + kB0.w*q0.w
                + kB1.x*q1.x + kB1.y*q1.y + kB1.z*q1.z + kB1.w*q1.w
                + kB2.x*q2.x + kB2.y*q2.y + kB2.z*q2.z + kB2.w*q2.w
                + kB3.x*q3.x + kB3.y*q3.y + kB3.z*q3.z + kB3.w*q3.w;
      scB[t] = acc * 0.25f; }
  }

  // exact softmax (identical numerics to validated path), A/B interleaved
  float mxA[4], mxB[4], exA[4], exB[4], smA[4], smB[4], aA[4], aB[4];
#pragma unroll
  for (int t = 0; t < 4; ++t) { mxA[t] = scA[t]; mxB[t] = scB[t]; }
#pragma unroll
  for (int off = 32; off >= 1; off >>= 1)
#pragma unroll
    for (int t = 0; t < 4; ++t) {
      mxA[t] = fmaxf(mxA[t], __shfl_xor(mxA[t], off));
      mxB[t] = fmaxf(mxB[t], __shfl_xor(mxB[t], off));
    }
#pragma unroll
  for (int t = 0; t < 4; ++t) {
    exA[t] = __expf(scA[t] - mxA[t]); smA[t] = exA[t];
    exB[t] = __expf(scB[t] - mxB[t]); smB[t] = exB[t];
  }
#pragma unroll
  for (int off = 32; off >= 1; off >>= 1)
#pragma unroll
    for (int t = 0; t < 4; ++t) {
      smA[t] += __shfl_xor(smA[t], off);
      smB[t] += __shfl_xor(smB[t], off);
    }
#pragma unroll
  for (int t = 0; t < 4; ++t) {
    aA[t] = exA[t] / smA[t]; als_t[wid][0][t][lane] = aA[t];
    aB[t] = exB[t] / smB[t]; als_t[wid][1][t][lane] = aB[t];
  }
  *(float4*)&als_k[wid][0][lane >> 4][lane & 15][0] = make_float4(aA[0], aA[1], aA[2], aA[3]);
  *(float4*)&als_k[wid][1][lane >> 4][lane & 15][0] = make_float4(aB[0], aB[1], aB[2], aB[3]);
  wave_sync();

  // stable top-16 by rank counting (value desc, index asc), both units
#pragma unroll
  for (int tt = 0; tt < 4; ++tt) {
    float mvA = aA[tt], mvB = aB[tt];
    int rkA = 0, rkB = 0;
    for (int j4 = 0; j4 < 64; j4 += 4) {
      float4 vA = *(const float4*)&als_t[wid][0][tt][j4];
      float4 vB = *(const float4*)&als_t[wid][1][tt][j4];
      rkA += (vA.x > mvA) || (vA.x == mvA && (j4 + 0) < lane);
      rkB += (vB.x > mvB) || (vB.x == mvB && (j4 + 0) < lane);
      rkA += (vA.y > mvA) || (vA.y == mvA && (j4 + 1) < lane);
      rkB += (vB.y > mvB) || (vB.y == mvB && (j4 + 1) < lane);
      rkA += (vA.z > mvA) || (vA.z == mvA && (j4 + 2) < lane);
      rkB += (vB.z > mvB) || (vB.z == mvB && (j4 + 2) < lane);
      rkA += (vA.w > mvA) || (vA.w == mvA && (j4 + 3) < lane);
      rkB += (vB.w > mvB) || (vB.w == mvB && (j4 + 3) < lane);
    }
    int rowT = 2 * hb + (tt >> 1);
    if (rkA < 16) {
      int n1 = rowT * 64 + 2 * wbA + (tt & 1);
      ti_out[((size_t)bh * 4096 + n1) * 16 + rkA] = candA;
    }
    if (rkB < 16) {
      int n1 = rowT * 64 + 2 * wbB + (tt & 1);
      ti_out[((size_t)bh * 4096 + n1) * 16 + rkB] = candB;
    }
  }

  // message: lane = (g, dd); group g covers candidates g*16..+15, all 4 t
  {
    const int g = lane >> 4, dd = lane & 15;
    float aA0 = 0, aA1 = 0, aA2 = 0, aA3 = 0;
    float aB0 = 0, aB1 = 0, aB2 = 0, aB3 = 0;
#pragma unroll
    for (int k4 = 0; k4 < 16; k4 += 4) {
      int4 cvA = *(const int4*)&cofs[wid][0][g * 16 + k4];
      int4 cvB = *(const int4*)&cofs[wid][1][g * 16 + k4];
      float vA0 = vt[cvA.x + dd], vA1 = vt[cvA.y + dd];
      float vA2 = vt[cvA.z + dd], vA3 = vt[cvA.w + dd];
      float vB0 = vt[cvB.x + dd], vB1 = vt[cvB.y + dd];
      float vB2 = vt[cvB.z + dd], vB3 = vt[cvB.w + dd];
      float4 wA0 = *(const float4*)&als_k[wid][0][g][k4 + 0][0];
      float4 wA1 = *(const float4*)&als_k[wid][0][g][k4 + 1][0];
      float4 wA2 = *(const float4*)&als_k[wid][0][g][k4 + 2][0];
      float4 wA3 = *(const float4*)&als_k[wid][0][g][k4 + 3][0];
      float4 wB0 = *(const float4*)&als_k[wid][1][g][k4 + 0][0];
      float4 wB1 = *(const float4*)&als_k[wid][1][g][k4 + 1][0];
      float4 wB2 = *(const float4*)&als_k[wid][1][g][k4 + 2][0];
      float4 wB3 = *(const float4*)&als_k[wid][1][g][k4 + 3][0];
      aA0 += wA0.x * vA0; aA1 += wA0.y * vA0; aA2 += wA0.z * vA0; aA3 += wA0.w * vA0;
      aA0 += wA1.x * vA1; aA1 += wA1.y * vA1; aA2 += wA1.z * vA1; aA3 += wA1.w * vA1;
      aA0 += wA2.x * vA2; aA1 += wA2.y * vA2; aA2 += wA2.z * vA2; aA3 += wA2.w * vA2;
      aA0 += wA3.x * vA3; aA1 += wA3.y * vA3; aA2 += wA3.z * vA3; aA3 += wA3.w * vA3;
      aB0 += wB0.x * vB0; aB1 += wB0.y * vB0; aB2 += wB0.z * vB0; aB3 += wB0.w * vB0;
      aB0 += wB1.x * vB1; aB1 += wB1.y * vB1; aB2 += wB1.z * vB1; aB3 += wB1.w * vB1;
      aB0 += wB2.x * vB2; aB1 += wB2.y * vB2; aB2 += wB2.z * vB2; aB3 += wB2.w * vB2;
      aB0 += wB3.x * vB3; aB1 += wB3.y * vB3; aB2 += wB3.z * vB3; aB3 += wB3.w * vB3;
    }
    aA0 += __shfl_xor(aA0, 16); aA0 += __shfl_xor(aA0, 32);
    aA1 += __shfl_xor(aA1, 16); aA1 += __shfl_xor(aA1, 32);
    aA2 += __shfl_xor(aA2, 16); aA2 += __shfl_xor(aA2, 32);
    aA3 += __shfl_xor(aA3, 16); aA3 += __shfl_xor(aA3, 32);
    aB0 += __shfl_xor(aB0, 16); aB0 += __shfl_xor(aB0, 32);
    aB1 += __shfl_xor(aB1, 16); aB1 += __shfl_xor(aB1, 32);
    aB2 += __shfl_xor(aB2, 16); aB2 += __shfl_xor(aB2, 32);
    aB3 += __shfl_xor(aB3, 16); aB3 += __shfl_xor(aB3, 32);
    float msgA = (g & 2) ? ((g & 1) ? aA3 : aA2) : ((g & 1) ? aA1 : aA0);
    float msgB = (g & 2) ? ((g & 1) ? aB3 : aB2) : ((g & 1) ? aB1 : aB0);
    int mA = hb * 128 + (wbA >> 3) * 32 + (g >> 1) * 16 + (wbA & 7) * 2 + (g & 1);
    int mB = hb * 128 + (wbB >> 3) * 32 + (g >> 1) * 16 + (wbB & 7) * 2 + (g & 1);
    mc[(b * 4096 + mA) * C + hD + dd] = msgA;
    mc[(b * 4096 + mB) * C + hD + dd] = msgB;
  }
}

// ---------------- K4: fine attention, 2 units per wave (unchanged) --------
__global__ __launch_bounds__(256) void attn_fine2(
    const float* __restrict__ qt, const float* __restrict__ kt,
    const float* __restrict__ vt, const int* __restrict__ tin,
    const float* __restrict__ mc, const float* __restrict__ weight,
    float* __restrict__ out)
{
  __shared__ alignas(16) float als_k[4][2][4][17][4]; // [wave][u][g][kk][t]
  __shared__ alignas(16) float qls[4][2][4][16];
  __shared__ alignas(16) int   cofs[4][2][64];

  const int lane = threadIdx.x & 63;
  const int wid  = threadIdx.x >> 6;
  const int wg = (blockIdx.x & 7) * 1024 + (blockIdx.x >> 3); // XCD swizzle
  const int p  = wg * 4 + wid;        // pair id [0, 32768)
  const int wb2 = p & 31;
  const int hb  = (p >> 5) & 63;
  const int h   = (p >> 11) & 7;
  const int b   = p >> 14;
  const int bh  = b * 8 + h;
  const int nA  = hb * 64 + wb2 * 2;  // unit A fine-n; B = nA+1
  const int hD  = h * 16;

  // q loads (both units)
  { int t = lane >> 4, dd = lane & 15;
    int rowq = (hb * 2 + (t >> 1)) * 128;
    qls[wid][0][t][dd] = qt[((size_t)bh * 16384 + rowq + wb2 * 4     + (t & 1)) * 16 + dd];
    qls[wid][1][t][dd] = qt[((size_t)bh * 16384 + rowq + wb2 * 4 + 2 + (t & 1)) * 16 + dd];
  }
  // parents -> candidate element offsets
  int off0A, off0B;
  { int kp = lane >> 2, c = lane & 3;
    int tA = tin[((size_t)bh * 4096 + nA    ) * 16 + kp];
    int tB = tin[((size_t)bh * 4096 + nA + 1) * 16 + kp];
    int candA = (2 * (tA >> 6) + (c >> 1)) * 128 + 2 * (tA & 63) + (c & 1);
    int candB = (2 * (tB >> 6) + (c >> 1)) * 128 + 2 * (tB & 63) + (c & 1);
    off0A = (bh * 16384 + candA) * 16;
    off0B = (bh * 16384 + candB) * 16;
    cofs[wid][0][lane] = off0A;
    cofs[wid][1][lane] = off0B;
  }
  wave_sync();

  // K gathers (two independent 64B rows in flight)
  float4 kA0, kA1, kA2, kA3, kB0, kB1, kB2, kB3;
  { const float4* kv = (const float4*)(kt + off0A); kA0 = kv[0]; kA1 = kv[1]; kA2 = kv[2]; kA3 = kv[3]; }
  { const float4* kv = (const float4*)(kt + off0B); kB0 = kv[0]; kB1 = kv[1]; kB2 = kv[2]; kB3 = kv[3]; }

  float ex0[4], ex1[4];
#pragma unroll
  for (int t = 0; t < 4; ++t) {
    { const float4* qv = (const float4*)qls[wid][0][t];
      float4 q0 = qv[0], q1 = qv[1], q2 = qv[2], q3 = qv[3];
      float acc = kA0.x*q0.x + kA0.y*q0.y + kA0.z*q0.z + kA0.w*q0.w
                + kA1.x*q1.x + kA1.y*q1.y + kA1.z*q1.z + kA1.w*q1.w
                + kA2.x*q2.x + kA2.y*q2.y + kA2.z*q2.z + kA2.w*q2.w
                + kA3.x*q3.x + kA3.y*q3.y + kA3.z*q3.z + kA3.w*q3.w;
      ex0[t] = __expf(acc * 0.25f); }
    { const float4* qv = (const float4*)qls[wid][1][t];
      float4 q0 = qv[0], q1 = qv[1], q2 = qv[2], q3 = qv[3];
      float acc = kB0.x*q0.x + kB0.y*q0.y + kB0.z*q0.z + kB0.w*q0.w
                + kB1.x*q1.x + kB1.y*q1.y + kB1.z*q1.z + kB1.w*q1.w
                + kB2.x*q2.x + kB2.y*q2.y + kB2.z*q2.z + kB2.w*q2.w
                + kB3.x*q3.x + kB3.y*q3.y + kB3.z*q3.z + kB3.w*q3.w;
      ex1[t] = __expf(acc * 0.25f); }
  }
  *(float4*)&als_k[wid][0][lane >> 4][lane & 15][0] = make_float4(ex0[0], ex0[1], ex0[2], ex0[3]);
  *(float4*)&als_k[wid][1][lane >> 4][lane & 15][0] = make_float4(ex1[0], ex1[1], ex1[2], ex1[3]);
  wave_sync();

  const int g = lane >> 4, dd = lane & 15;
  // prefetch coarse-message rows (latency hidden under trees + loop)
  float mcvA = mc[((size_t)b * 4096 + nA    ) * C + hD + dd];
  float mcvB = mc[((size_t)b * 4096 + nA + 1) * C + hD + dd];

  // denominators via interleaved shuffle trees (DS pipe, off VALU path)
  float smA[4], smB[4];
#pragma unroll
  for (int t = 0; t < 4; ++t) { smA[t] = ex0[t]; smB[t] = ex1[t]; }
#pragma unroll
  for (int off = 32; off >= 1; off >>= 1)
#pragma unroll
    for (int t = 0; t < 4; ++t) {
      smA[t] += __shfl_xor(smA[t], off);
      smB[t] += __shfl_xor(smB[t], off);
    }

  // message loops, A/B interleaved
  float aA0 = 0, aA1 = 0, aA2 = 0, aA3 = 0;
  float aB0 = 0, aB1 = 0, aB2 = 0, aB3 = 0;
#pragma unroll
  for (int k4 = 0; k4 < 16; k4 += 4) {
    int4 cvA = *(const int4*)&cofs[wid][0][g * 16 + k4];
    int4 cvB = *(const int4*)&cofs[wid][1][g * 16 + k4];
    float vA0 = vt[cvA.x + dd], vA1 = vt[cvA.y + dd];
    float vA2 = vt[cvA.z + dd], vA3 = vt[cvA.w + dd];
    float vB0 = vt[cvB.x + dd], vB1 = vt[cvB.y + dd];
    float vB2 = vt[cvB.z + dd], vB3 = vt[cvB.w + dd];
    float4 wA0 = *(const float4*)&als_k[wid][0][g][k4 + 0][0];
    float4 wA1 = *(const float4*)&als_k[wid][0][g][k4 + 1][0];
    float4 wA2 = *(const float4*)&als_k[wid][0][g][k4 + 2][0];
    float4 wA3 = *(const float4*)&als_k[wid][0][g][k4 + 3][0];
    float4 wB0 = *(const float4*)&als_k[wid][1][g][k4 + 0][0];
    float4 wB1 = *(const float4*)&als_k[wid][1][g][k4 + 1][0];
    float4 wB2 = *(const float4*)&als_k[wid][1][g][k4 + 2][0];
    float4 wB3 = *(const float4*)&als_k[wid][1][g][k4 + 3][0];
    aA0 += wA0.x * vA0; aA1 += wA0.y * vA0; aA2 += wA0.z * vA0; aA3 += wA0.w * vA0;
    aA0 += wA1.x * vA1; aA1 += wA1.y * vA1; aA2 += wA1.z * vA1; aA3 += wA1.w * vA1;
    aA0 += wA2.x * vA2; aA1 += wA2.y * vA2; aA2 += wA2.z * vA2; aA3 += wA2.w * vA2;
    aA0 += wA3.x * vA3; aA1 += wA3.y * vA3; aA2 += wA3.z * vA3; aA3 += wA3.w * vA3;
    aB0 += wB0.x * vB0; aB1 += wB0.y * vB0; aB2 += wB0.z * vB0; aB3 += wB0.w * vB0;
    aB0 += wB1.x * vB1; aB1 += wB1.y * vB1; aB2 += wB1.z * vB1; aB3 += wB1.w * vB1;
    aB0 += wB2.x * vB2; aB1 += wB2.y * vB2; aB2 += wB2.z * vB2; aB3 += wB2.w * vB2;
    aB0 += wB3.x * vB3; aB1 += wB3.y * vB3; aB2 += wB3.z * vB3; aB3 += wB3.w * vB3;
  }
  aA0 += __shfl_xor(aA0, 16); aA0 += __shfl_xor(aA0, 32);
  aA1 += __shfl_xor(aA1, 16); aA1 += __shfl_xor(aA1, 32);
  aA2 += __shfl_xor(aA2, 16); aA2 += __shfl_xor(aA2, 32);
  aA3 += __shfl_xor(aA3, 16); aA3 += __shfl_xor(aA3, 32);
  aB0 += __shfl_xor(aB0, 16); aB0 += __shfl_xor(aB0, 32);
  aB1 += __shfl_xor(aB1, 16); aB1 += __shfl_xor(aB1, 32);
  aB2 += __shfl_xor(aB2, 16); aB2 += __shfl_xor(aB2, 32);
  aB3 += __shfl_xor(aB3, 16); aB3 += __shfl_xor(aB3, 32);

  float msgA = (g & 2) ? ((g & 1) ? aA3 : aA2) : ((g & 1) ? aA1 : aA0);
  float msgB = (g & 2) ? ((g & 1) ? aB3 : aB2) : ((g & 1) ? aB1 : aB0);
  float smvA = (g & 2) ? ((g & 1) ? smA[3] : smA[2]) : ((g & 1) ? smA[1] : smA[0]);
  float smvB = (g & 2) ? ((g & 1) ? smB[3] : smB[2]) : ((g & 1) ? smB[1] : smB[0]);
  msgA /= smvA;
  msgB /= smvB;

  float w0 = weight[0], w1 = weight[1];
  float wm = fmaxf(w0, w1);
  float e0 = __expf(w0 - wm), e1 = __expf(w1 - wm);
  float inv = 1.0f / (e0 + e1);
  int rowq = (hb * 2 + (g >> 1)) * 128;
  out[((size_t)b * 16384 + rowq + wb2 * 4     + (g & 1)) * C + hD + dd] =
      (e0 * inv) * mcvA + (e1 * inv) * msgA;
  out[((size_t)b * 16384 + rowq + wb2 * 4 + 2 + (g & 1)) * C + hD + dd] =
      (e0 * inv) * mcvB + (e1 * inv) * msgB;
}

extern "C" void kernel_launch(void* const* d_in, const int* in_sizes, int n_in,
                              void* d_out, int out_size, void* d_ws, size_t ws_size,
                              hipStream_t stream) {
  const float* q_fine   = (const float*)d_in[0];
  const float* q_coarse = (const float*)d_in[1];
  const float* k_fine   = (const float*)d_in[2];
  const float* k_coarse = (const float*)d_in[3];
  const float* v_fine   = (const float*)d_in[4];
  const float* v_coarse = (const float*)d_in[5];
  const float* weight   = (const float*)d_in[6];
  const int*   topk_pos = (const int*)d_in[7];
  float* out = (float*)d_out;

  const int PF = 16384, PC = 4096;
  float* ws   = (float*)d_ws;
  float* qt_f = ws;                 // head-major [b][h][P][16]
  float* kt_f = qt_f + 2 * PF * C;
  float* vt_f = kt_f + 2 * PF * C;
  float* qt_c = vt_f + 2 * PF * C;
  float* kt_c = qt_c + 2 * PC * C;
  float* vt_c = kt_c + 2 * PC * C;
  float* mc   = vt_c + 2 * PC * C;          // 2*4096*C (permuted coarse message)
  int*   ti   = (int*)(mc + 2 * 4096 * C);  // head-major [b][h][4096][16]

  dim3 blk(256);
  // K1: coarse transpose (small, streaming)
  transpose_coarse<<<768, blk, 0, stream>>>(q_coarse, k_coarse, v_coarse,
                                            qt_c, kt_c, vt_c);
  // K2: coarse attn, 2 units/wave -> 8192 pairs / 4 per block
  attn_coarse2<<<2048, blk, 0, stream>>>(qt_c, kt_c, vt_c, topk_pos, mc, ti);
  // K3: fine transpose (pure streaming, runs alone)
  transpose_fine<<<3072, blk, 0, stream>>>(q_fine, k_fine, v_fine,
                                           qt_f, kt_f, vt_f);
  // K4: fine attn, 2 units/wave -> 32768 pairs / 4 per block
  attn_fine2<<<8192, blk, 0, stream>>>(qt_f, kt_f, vt_f, ti, mc, weight, out);
}

// Round 8
// 118.524 us; speedup vs baseline: 1.0999x; 1.0999x over previous
//
#include <hip/hip_runtime.h>

#define C 128   // channels = nh*d = 8*16

// wave-local LDS fence: all attn LDS buffers are per-wave.
__device__ __forceinline__ void wave_sync() {
  __builtin_amdgcn_wave_barrier();
  asm volatile("s_waitcnt lgkmcnt(0)" ::: "memory");
  __builtin_amdgcn_wave_barrier();
}

// transpose one 64x64 tile of [b, C, P] -> head-major [b, h, P, 16]
__device__ __forceinline__ void transpose_tile(const float* __restrict__ in,
                                               float* __restrict__ out, int P,
                                               int tx, int chHalf, int b,
                                               float (*tile)[65]) {
  int posBase = tx * 64;
  int chBase  = chHalf * 64;
  int tid = threadIdx.x;
  int lp = tid & 63;
  int lr = tid >> 6;
  const float* ip = in + (size_t)b * C * P;
  float* op = out + (size_t)b * C * P;
#pragma unroll
  for (int it = 0; it < 16; ++it) {
    int ch = lr + it * 4;
    tile[ch][lp] = ip[(size_t)(chBase + ch) * P + posBase + lp];
  }
  __syncthreads();
  int ch2 = chBase + lp;
  int hh = ch2 >> 4, dd = ch2 & 15;
#pragma unroll
  for (int it = 0; it < 16; ++it) {
    int pl = lr + it * 4;
    op[((size_t)hh * P + posBase + pl) * 16 + dd] = tile[lp][pl];
  }
}

// ---------------- K1: coarse transpose (768 blocks) ----------------
__global__ __launch_bounds__(256) void transpose_coarse(
    const float* __restrict__ q, const float* __restrict__ k,
    const float* __restrict__ v, float* __restrict__ qo,
    float* __restrict__ ko, float* __restrict__ vo) {
  __shared__ alignas(16) float tile[64][65];
  int idx = blockIdx.x;
  int tx = idx & 63;
  int ty = (idx >> 6) % 6;
  int tz = idx / 384;
  int sel = ty >> 1;
  const float* in = sel == 0 ? q : sel == 1 ? k : v;
  float* out      = sel == 0 ? qo : sel == 1 ? ko : vo;
  transpose_tile(in, out, 4096, tx, ty & 1, tz, tile);
}

// ---------------- K3: fine transpose (3072 blocks, pure streaming) --------
__global__ __launch_bounds__(256) void transpose_fine(
    const float* __restrict__ q, const float* __restrict__ k,
    const float* __restrict__ v, float* __restrict__ qo,
    float* __restrict__ ko, float* __restrict__ vo) {
  __shared__ alignas(16) float tile[64][65];
  int idx = blockIdx.x;
  int tx = idx & 255;
  int ty = (idx >> 8) % 6;
  int tz = idx / 1536;
  int sel = ty >> 1;
  const float* in = sel == 0 ? q : sel == 1 ? k : v;
  float* out      = sel == 0 ? qo : sel == 1 ? ko : vo;
  transpose_tile(in, out, 16384, tx, ty & 1, tz, tile);
}

// ---------------- K2: coarse attention, 1 unit per wave (proven 48-VGPR
//  path: exact softmax + stable rank, validated numerics). Pairing this
//  level regressed (R7): 2 units push VGPR past the 64 cliff and the
//  latency-chained rank loop loses its TLP. ---------------------------------
__global__ __launch_bounds__(256) void attn_coarse(
    const float* __restrict__ qt, const float* __restrict__ kt,
    const float* __restrict__ vt, const int* __restrict__ parents,
    float* __restrict__ mc, int* __restrict__ ti_out)
{
  __shared__ alignas(16) float als_t[4][4][64];    // [wave][t][k]
  __shared__ alignas(16) float als_k[4][4][17][4]; // [wave][g][kk][t]
  __shared__ alignas(16) float qls[4][4][16];
  __shared__ alignas(16) int   cofs[4][64];

  const int lane = threadIdx.x & 63;
  const int wid  = threadIdx.x >> 6;
  const int wg = (blockIdx.x & 7) * 512 + (blockIdx.x >> 3);  // XCD swizzle
  const int u  = wg * 4 + wid;
  const int h  = u & 7;
  const int bn = u >> 3;
  const int n  = bn & 1023;
  const int b  = bn >> 10;
  const int hb = n >> 5;
  const int wb = n & 31;
  const int hD = h * 16;
  const int bh = b * 8 + h;

  { int t = lane >> 4, dd = lane & 15;
    int pix = (hb * 2 + (t >> 1)) * 64 + (wb * 2 + (t & 1));
    qls[wid][t][dd] = qt[((size_t)bh * 4096 + pix) * 16 + dd]; }
  int cand, off0;
  { int kp = lane >> 2, c = lane & 3;
    int r  = parents[(size_t)b * 131072          + n * 128 + kp * 8 + h];
    int cc = parents[(size_t)b * 131072 + 262144 + n * 128 + kp * 8 + h];
    cand = (2 * r + (c >> 1)) * 64 + 2 * cc + (c & 1);
    off0 = (bh * 4096 + cand) * 16;
    cofs[wid][lane] = off0; }
  wave_sync();

  const float4* kv4 = (const float4*)(kt + off0);
  float4 k0 = kv4[0], k1 = kv4[1], k2 = kv4[2], k3 = kv4[3];
  float sc[4];
#pragma unroll
  for (int t = 0; t < 4; ++t) {
    const float4* qv = (const float4*)qls[wid][t];
    float4 q0 = qv[0], q1 = qv[1], q2 = qv[2], q3 = qv[3];
    float acc = k0.x*q0.x + k0.y*q0.y + k0.z*q0.z + k0.w*q0.w
              + k1.x*q1.x + k1.y*q1.y + k1.z*q1.z + k1.w*q1.w
              + k2.x*q2.x + k2.y*q2.y + k2.z*q2.z + k2.w*q2.w
              + k3.x*q3.x + k3.y*q3.y + k3.z*q3.z + k3.w*q3.w;
    sc[t] = acc * 0.25f;
  }

  // exact softmax (identical numerics to validated path)
  float mx[4], ex[4], sm[4], a[4];
#pragma unroll
  for (int t = 0; t < 4; ++t) mx[t] = sc[t];
#pragma unroll
  for (int off = 32; off >= 1; off >>= 1)
#pragma unroll
    for (int t = 0; t < 4; ++t) mx[t] = fmaxf(mx[t], __shfl_xor(mx[t], off));
#pragma unroll
  for (int t = 0; t < 4; ++t) { ex[t] = __expf(sc[t] - mx[t]); sm[t] = ex[t]; }
#pragma unroll
  for (int off = 32; off >= 1; off >>= 1)
#pragma unroll
    for (int t = 0; t < 4; ++t) sm[t] += __shfl_xor(sm[t], off);
#pragma unroll
  for (int t = 0; t < 4; ++t) { a[t] = ex[t] / sm[t]; als_t[wid][t][lane] = a[t]; }
  *(float4*)&als_k[wid][lane >> 4][lane & 15][0] = make_float4(a[0], a[1], a[2], a[3]);
  wave_sync();

  // stable top-16 by rank counting (value desc, index asc)
#pragma unroll
  for (int tt = 0; tt < 4; ++tt) {
    float myv = a[tt];
    int rank = 0;
    for (int j4 = 0; j4 < 64; j4 += 4) {
      float4 vj = *(const float4*)&als_t[wid][tt][j4];
      rank += (vj.x > myv) || (vj.x == myv && (j4 + 0) < lane);
      rank += (vj.y > myv) || (vj.y == myv && (j4 + 1) < lane);
      rank += (vj.z > myv) || (vj.z == myv && (j4 + 2) < lane);
      rank += (vj.w > myv) || (vj.w == myv && (j4 + 3) < lane);
    }
    if (rank < 16) {
      int n1 = (2 * hb + (tt >> 1)) * 64 + 2 * wb + (tt & 1);
      ti_out[((size_t)bh * 4096 + n1) * 16 + rank] = cand;
    }
  }

  // message: lane = (g, dd); group g covers candidates g*16..+15, all 4 t
  {
    const int g = lane >> 4, dd = lane & 15;
    float acc0 = 0.f, acc1 = 0.f, acc2 = 0.f, acc3 = 0.f;
#pragma unroll
    for (int k4 = 0; k4 < 16; k4 += 4) {
      int4 cv = *(const int4*)&cofs[wid][g * 16 + k4];
      float4 a0 = *(const float4*)&als_k[wid][g][k4 + 0][0];
      float4 a1 = *(const float4*)&als_k[wid][g][k4 + 1][0];
      float4 a2 = *(const float4*)&als_k[wid][g][k4 + 2][0];
      float4 a3 = *(const float4*)&als_k[wid][g][k4 + 3][0];
      float v0 = vt[cv.x + dd];
      float v1 = vt[cv.y + dd];
      float v2 = vt[cv.z + dd];
      float v3 = vt[cv.w + dd];
      acc0 += a0.x * v0; acc1 += a0.y * v0; acc2 += a0.z * v0; acc3 += a0.w * v0;
      acc0 += a1.x * v1; acc1 += a1.y * v1; acc2 += a1.z * v1; acc3 += a1.w * v1;
      acc0 += a2.x * v2; acc1 += a2.y * v2; acc2 += a2.z * v2; acc3 += a2.w * v2;
      acc0 += a3.x * v3; acc1 += a3.y * v3; acc2 += a3.z * v3; acc3 += a3.w * v3;
    }
    acc0 += __shfl_xor(acc0, 16); acc0 += __shfl_xor(acc0, 32);
    acc1 += __shfl_xor(acc1, 16); acc1 += __shfl_xor(acc1, 32);
    acc2 += __shfl_xor(acc2, 16); acc2 += __shfl_xor(acc2, 32);
    acc3 += __shfl_xor(acc3, 16); acc3 += __shfl_xor(acc3, 32);
    float msg = (g & 2) ? ((g & 1) ? acc3 : acc2) : ((g & 1) ? acc1 : acc0);
    int m = hb * 128 + (wb >> 3) * 32 + (g >> 1) * 16 + (wb & 7) * 2 + (g & 1);
    mc[(b * 4096 + m) * C + hD + dd] = msg;
  }
}

// ---------------- K4: fine attention, 2 units per wave (proven) -----------
__global__ __launch_bounds__(256) void attn_fine2(
    const float* __restrict__ qt, const float* __restrict__ kt,
    const float* __restrict__ vt, const int* __restrict__ tin,
    const float* __restrict__ mc, const float* __restrict__ weight,
    float* __restrict__ out)
{
  __shared__ alignas(16) float als_k[4][2][4][17][4]; // [wave][u][g][kk][t]
  __shared__ alignas(16) float qls[4][2][4][16];
  __shared__ alignas(16) int   cofs[4][2][64];

  const int lane = threadIdx.x & 63;
  const int wid  = threadIdx.x >> 6;
  const int wg = (blockIdx.x & 7) * 1024 + (blockIdx.x >> 3); // XCD swizzle
  const int p  = wg * 4 + wid;        // pair id [0, 32768)
  const int wb2 = p & 31;
  const int hb  = (p >> 5) & 63;
  const int h   = (p >> 11) & 7;
  const int b   = p >> 14;
  const int bh  = b * 8 + h;
  const int nA  = hb * 64 + wb2 * 2;  // unit A fine-n; B = nA+1
  const int hD  = h * 16;

  // q loads (both units)
  { int t = lane >> 4, dd = lane & 15;
    int rowq = (hb * 2 + (t >> 1)) * 128;
    qls[wid][0][t][dd] = qt[((size_t)bh * 16384 + rowq + wb2 * 4     + (t & 1)) * 16 + dd];
    qls[wid][1][t][dd] = qt[((size_t)bh * 16384 + rowq + wb2 * 4 + 2 + (t & 1)) * 16 + dd];
  }
  // parents -> candidate element offsets
  int off0A, off0B;
  { int kp = lane >> 2, c = lane & 3;
    int tA = tin[((size_t)bh * 4096 + nA    ) * 16 + kp];
    int tB = tin[((size_t)bh * 4096 + nA + 1) * 16 + kp];
    int candA = (2 * (tA >> 6) + (c >> 1)) * 128 + 2 * (tA & 63) + (c & 1);
    int candB = (2 * (tB >> 6) + (c >> 1)) * 128 + 2 * (tB & 63) + (c & 1);
    off0A = (bh * 16384 + candA) * 16;
    off0B = (bh * 16384 + candB) * 16;
    cofs[wid][0][lane] = off0A;
    cofs[wid][1][lane] = off0B;
  }
  wave_sync();

  // K gathers (two independent 64B rows in flight)
  float4 kA0, kA1, kA2, kA3, kB0, kB1, kB2, kB3;
  { const float4* kv = (const float4*)(kt + off0A); kA0 = kv[0]; kA1 = kv[1]; kA2 = kv[2]; kA3 = kv[3]; }
  { const float4* kv = (const float4*)(kt + off0B); kB0 = kv[0]; kB1 = kv[1]; kB2 = kv[2]; kB3 = kv[3]; }

  float ex0[4], ex1[4];
#pragma unroll
  for (int t = 0; t < 4; ++t) {
    { const float4* qv = (const float4*)qls[wid][0][t];
      float4 q0 = qv[0], q1 = qv[1], q2 = qv[2], q3 = qv[3];
      float acc = kA0.x*q0.x + kA0.y*q0.y + kA0.z*q0.z + kA0.w*q0.w
                + kA1.x*q1.x + kA1.y*q1.y + kA1.z*q1.z + kA1.w*q1.w
                + kA2.x*q2.x + kA2.y*q2.y + kA2.z*q2.z + kA2.w*q2.w
                + kA3.x*q3.x + kA3.y*q3.y + kA3.z*q3.z + kA3.w*q3.w;
      ex0[t] = __expf(acc * 0.25f); }
    { const float4* qv = (const float4*)qls[wid][1][t];
      float4 q0 = qv[0], q1 = qv[1], q2 = qv[2], q3 = qv[3];
      float acc = kB0.x*q0.x + kB0.y*q0.y + kB0.z*q0.z + kB0.w*q0.w
                + kB1.x*q1.x + kB1.y*q1.y + kB1.z*q1.z + kB1.w*q1.w
                + kB2.x*q2.x + kB2.y*q2.y + kB2.z*q2.z + kB2.w*q2.w
                + kB3.x*q3.x + kB3.y*q3.y + kB3.z*q3.z + kB3.w*q3.w;
      ex1[t] = __expf(acc * 0.25f); }
  }
  *(float4*)&als_k[wid][0][lane >> 4][lane & 15][0] = make_float4(ex0[0], ex0[1], ex0[2], ex0[3]);
  *(float4*)&als_k[wid][1][lane >> 4][lane & 15][0] = make_float4(ex1[0], ex1[1], ex1[2], ex1[3]);
  wave_sync();

  const int g = lane >> 4, dd = lane & 15;
  // prefetch coarse-message rows (latency hidden under trees + loop)
  float mcvA = mc[((size_t)b * 4096 + nA    ) * C + hD + dd];
  float mcvB = mc[((size_t)b * 4096 + nA + 1) * C + hD + dd];

  // denominators via interleaved shuffle trees (DS pipe, off VALU path)
  float smA[4], smB[4];
#pragma unroll
  for (int t = 0; t < 4; ++t) { smA[t] = ex0[t]; smB[t] = ex1[t]; }
#pragma unroll
  for (int off = 32; off >= 1; off >>= 1)
#pragma unroll
    for (int t = 0; t < 4; ++t) {
      smA[t] += __shfl_xor(smA[t], off);
      smB[t] += __shfl_xor(smB[t], off);
    }

  // message loops, A/B interleaved
  float aA0 = 0, aA1 = 0, aA2 = 0, aA3 = 0;
  float aB0 = 0, aB1 = 0, aB2 = 0, aB3 = 0;
#pragma unroll
  for (int k4 = 0; k4 < 16; k4 += 4) {
    int4 cvA = *(const int4*)&cofs[wid][0][g * 16 + k4];
    int4 cvB = *(const int4*)&cofs[wid][1][g * 16 + k4];
    float vA0 = vt[cvA.x + dd], vA1 = vt[cvA.y + dd];
    float vA2 = vt[cvA.z + dd], vA3 = vt[cvA.w + dd];
    float vB0 = vt[cvB.x + dd], vB1 = vt[cvB.y + dd];
    float vB2 = vt[cvB.z + dd], vB3 = vt[cvB.w + dd];
    float4 wA0 = *(const float4*)&als_k[wid][0][g][k4 + 0][0];
    float4 wA1 = *(const float4*)&als_k[wid][0][g][k4 + 1][0];
    float4 wA2 = *(const float4*)&als_k[wid][0][g][k4 + 2][0];
    float4 wA3 = *(const float4*)&als_k[wid][0][g][k4 + 3][0];
    float4 wB0 = *(const float4*)&als_k[wid][1][g][k4 + 0][0];
    float4 wB1 = *(const float4*)&als_k[wid][1][g][k4 + 1][0];
    float4 wB2 = *(const float4*)&als_k[wid][1][g][k4 + 2][0];
    float4 wB3 = *(const float4*)&als_k[wid][1][g][k4 + 3][0];
    aA0 += wA0.x * vA0; aA1 += wA0.y * vA0; aA2 += wA0.z * vA0; aA3 += wA0.w * vA0;
    aA0 += wA1.x * vA1; aA1 += wA1.y * vA1; aA2 += wA1.z * vA1; aA3 += wA1.w * vA1;
    aA0 += wA2.x * vA2; aA1 += wA2.y * vA2; aA2 += wA2.z * vA2; aA3 += wA2.w * vA2;
    aA0 += wA3.x * vA3; aA1 += wA3.y * vA3; aA2 += wA3.z * vA3; aA3 += wA3.w * vA3;
    aB0 += wB0.x * vB0; aB1 += wB0.y * vB0; aB2 += wB0.z * vB0; aB3 += wB0.w * vB0;
    aB0 += wB1.x * vB1; aB1 += wB1.y * vB1; aB2 += wB1.z * vB1; aB3 += wB1.w * vB1;
    aB0 += wB2.x * vB2; aB1 += wB2.y * vB2; aB2 += wB2.z * vB2; aB3 += wB2.w * vB2;
    aB0 += wB3.x * vB3; aB1 += wB3.y * vB3; aB2 += wB3.z * vB3; aB3 += wB3.w * vB3;
  }
  aA0 += __shfl_xor(aA0, 16); aA0 += __shfl_xor(aA0, 32);
  aA1 += __shfl_xor(aA1, 16); aA1 += __shfl_xor(aA1, 32);
  aA2 += __shfl_xor(aA2, 16); aA2 += __shfl_xor(aA2, 32);
  aA3 += __shfl_xor(aA3, 16); aA3 += __shfl_xor(aA3, 32);
  aB0 += __shfl_xor(aB0, 16); aB0 += __shfl_xor(aB0, 32);
  aB1 += __shfl_xor(aB1, 16); aB1 += __shfl_xor(aB1, 32);
  aB2 += __shfl_xor(aB2, 16); aB2 += __shfl_xor(aB2, 32);
  aB3 += __shfl_xor(aB3, 16); aB3 += __shfl_xor(aB3, 32);

  float msgA = (g & 2) ? ((g & 1) ? aA3 : aA2) : ((g & 1) ? aA1 : aA0);
  float msgB = (g & 2) ? ((g & 1) ? aB3 : aB2) : ((g & 1) ? aB1 : aB0);
  float smvA = (g & 2) ? ((g & 1) ? smA[3] : smA[2]) : ((g & 1) ? smA[1] : smA[0]);
  float smvB = (g & 2) ? ((g & 1) ? smB[3] : smB[2]) : ((g & 1) ? smB[1] : smB[0]);
  msgA /= smvA;
  msgB /= smvB;

  float w0 = weight[0], w1 = weight[1];
  float wm = fmaxf(w0, w1);
  float e0 = __expf(w0 - wm), e1 = __expf(w1 - wm);
  float inv = 1.0f / (e0 + e1);
  int rowq = (hb * 2 + (g >> 1)) * 128;
  out[((size_t)b * 16384 + rowq + wb2 * 4     + (g & 1)) * C + hD + dd] =
      (e0 * inv) * mcvA + (e1 * inv) * msgA;
  out[((size_t)b * 16384 + rowq + wb2 * 4 + 2 + (g & 1)) * C + hD + dd] =
      (e0 * inv) * mcvB + (e1 * inv) * msgB;
}

extern "C" void kernel_launch(void* const* d_in, const int* in_sizes, int n_in,
                              void* d_out, int out_size, void* d_ws, size_t ws_size,
                              hipStream_t stream) {
  const float* q_fine   = (const float*)d_in[0];
  const float* q_coarse = (const float*)d_in[1];
  const float* k_fine   = (const float*)d_in[2];
  const float* k_coarse = (const float*)d_in[3];
  const float* v_fine   = (const float*)d_in[4];
  const float* v_coarse = (const float*)d_in[5];
  const float* weight   = (const float*)d_in[6];
  const int*   topk_pos = (const int*)d_in[7];
  float* out = (float*)d_out;

  const int PF = 16384, PC = 4096;
  float* ws   = (float*)d_ws;
  float* qt_f = ws;                 // head-major [b][h][P][16]
  float* kt_f = qt_f + 2 * PF * C;
  float* vt_f = kt_f + 2 * PF * C;
  float* qt_c = vt_f + 2 * PF * C;
  float* kt_c = qt_c + 2 * PC * C;
  float* vt_c = kt_c + 2 * PC * C;
  float* mc   = vt_c + 2 * PC * C;          // 2*4096*C (permuted coarse message)
  int*   ti   = (int*)(mc + 2 * 4096 * C);  // head-major [b][h][4096][16]

  dim3 blk(256);
  // K1: coarse transpose (small, streaming)
  transpose_coarse<<<768, blk, 0, stream>>>(q_coarse, k_coarse, v_coarse,
                                            qt_c, kt_c, vt_c);
  // K2: coarse attn, 1 unit/wave (48-VGPR proven path), 4096 blocks
  attn_coarse<<<4096, blk, 0, stream>>>(qt_c, kt_c, vt_c, topk_pos, mc, ti);
  // K3: fine transpose (pure streaming, runs alone)
  transpose_fine<<<3072, blk, 0, stream>>>(q_fine, k_fine, v_fine,
                                           qt_f, kt_f, vt_f);
  // K4: fine attn, 2 units/wave -> 32768 pairs / 4 per block
  attn_fine2<<<8192, blk, 0, stream>>>(qt_f, kt_f, vt_f, ti, mc, weight, out);
}

// Round 9
// 110.680 us; speedup vs baseline: 1.1778x; 1.0709x over previous
//
#include <hip/hip_runtime.h>

#define C 128   // channels = nh*d = 8*16

// wave-local LDS fence: all attn LDS buffers are per-wave.
__device__ __forceinline__ void wave_sync() {
  __builtin_amdgcn_wave_barrier();
  asm volatile("s_waitcnt lgkmcnt(0)" ::: "memory");
  __builtin_amdgcn_wave_barrier();
}

// transpose one 64x64 tile of [b, C, P] -> head-major [b, h, P, 16]
__device__ __forceinline__ void transpose_tile(const float* __restrict__ in,
                                               float* __restrict__ out, int P,
                                               int tx, int chHalf, int b,
                                               float (*tile)[65]) {
  int posBase = tx * 64;
  int chBase  = chHalf * 64;
  int tid = threadIdx.x;
  int lp = tid & 63;
  int lr = tid >> 6;
  const float* ip = in + (size_t)b * C * P;
  float* op = out + (size_t)b * C * P;
#pragma unroll
  for (int it = 0; it < 16; ++it) {
    int ch = lr + it * 4;
    tile[ch][lp] = ip[(size_t)(chBase + ch) * P + posBase + lp];
  }
  __syncthreads();
  int ch2 = chBase + lp;
  int hh = ch2 >> 4, dd = ch2 & 15;
#pragma unroll
  for (int it = 0; it < 16; ++it) {
    int pl = lr + it * 4;
    op[((size_t)hh * P + posBase + pl) * 16 + dd] = tile[lp][pl];
  }
}

// ---------------- K1: coarse transpose (768 blocks) ----------------
__global__ __launch_bounds__(256) void transpose_coarse(
    const float* __restrict__ q, const float* __restrict__ k,
    const float* __restrict__ v, float* __restrict__ qo,
    float* __restrict__ ko, float* __restrict__ vo) {
  __shared__ alignas(16) float tile[64][65];
  int idx = blockIdx.x;
  int tx = idx & 63;
  int ty = (idx >> 6) % 6;
  int tz = idx / 384;
  int sel = ty >> 1;
  const float* in = sel == 0 ? q : sel == 1 ? k : v;
  float* out      = sel == 0 ? qo : sel == 1 ? ko : vo;
  transpose_tile(in, out, 4096, tx, ty & 1, tz, tile);
}

// ---------------- K2: coarse attn (blocks 0..4095, dispatched first) +
//  fine transpose backfill (blocks 4096..7167). Proven overlap (R6: 80us
//  vs 93us serial). Coarse attn decode is PLANE-MAJOR: an XCD's contiguous
//  unit chunk covers 2 (b,h) planes -> K/V gather working set 1.5MB, L2-fit.
__global__ __launch_bounds__(256) void fused_mid(
    const float* __restrict__ qf, const float* __restrict__ kf,
    const float* __restrict__ vf, float* __restrict__ qtf,
    float* __restrict__ ktf, float* __restrict__ vtf,
    const float* __restrict__ qt, const float* __restrict__ kt,
    const float* __restrict__ vt, const int* __restrict__ parents,
    float* __restrict__ mc, int* __restrict__ ti_out)
{
  __shared__ alignas(16) float lds[64 * 65];

  if (blockIdx.x >= 4096) {
    // ---- fine transpose ----
    int idx = blockIdx.x - 4096;
    int tx = idx & 255;
    int ty = (idx >> 8) % 6;
    int tz = idx / 1536;
    int sel = ty >> 1;
    const float* in = sel == 0 ? qf : sel == 1 ? kf : vf;
    float* out      = sel == 0 ? qtf : sel == 1 ? ktf : vtf;
    transpose_tile(in, out, 16384, tx, ty & 1, tz, (float (*)[65])lds);
    return;
  }

  // ---- coarse attention (validated numerics, W=64) ----
  float (*als_t)[4][64]    = (float (*)[4][64])   lds;          // 1024 f
  float (*als_k)[4][17][4] = (float (*)[4][17][4])(lds + 1024); // 1088 f
  float (*qls)[4][16]      = (float (*)[4][16])  (lds + 2112);  // 256 f
  int   (*cofs)[64]        = (int (*)[64])       (lds + 2368);  // 256 i

  const int abid = blockIdx.x;
  const int lane = threadIdx.x & 63;
  const int wid  = threadIdx.x >> 6;
  const int wg = (abid & 7) * 512 + (abid >> 3);  // XCD-chunked swizzle
  const int u  = wg * 4 + wid;
  // plane-major decode: consecutive u = same (b,h) plane
  const int n  = u & 1023;
  const int bh = u >> 10;          // [0,16)
  const int b  = bh >> 3;
  const int h  = bh & 7;
  const int hb = n >> 5;
  const int wb = n & 31;
  const int hD = h * 16;

  { int t = lane >> 4, dd = lane & 15;
    int pix = (hb * 2 + (t >> 1)) * 64 + (wb * 2 + (t & 1));
    qls[wid][t][dd] = qt[((size_t)bh * 4096 + pix) * 16 + dd]; }
  int cand, off0;
  { int kp = lane >> 2, c = lane & 3;
    int r  = parents[(size_t)b * 131072          + n * 128 + kp * 8 + h];
    int cc = parents[(size_t)b * 131072 + 262144 + n * 128 + kp * 8 + h];
    cand = (2 * r + (c >> 1)) * 64 + 2 * cc + (c & 1);
    off0 = (bh * 4096 + cand) * 16;
    cofs[wid][lane] = off0; }
  wave_sync();

  const float4* kv4 = (const float4*)(kt + off0);
  float4 k0 = kv4[0], k1 = kv4[1], k2 = kv4[2], k3 = kv4[3];
  float sc[4];
#pragma unroll
  for (int t = 0; t < 4; ++t) {
    const float4* qv = (const float4*)qls[wid][t];
    float4 q0 = qv[0], q1 = qv[1], q2 = qv[2], q3 = qv[3];
    float acc = k0.x*q0.x + k0.y*q0.y + k0.z*q0.z + k0.w*q0.w
              + k1.x*q1.x + k1.y*q1.y + k1.z*q1.z + k1.w*q1.w
              + k2.x*q2.x + k2.y*q2.y + k2.z*q2.z + k2.w*q2.w
              + k3.x*q3.x + k3.y*q3.y + k3.z*q3.z + k3.w*q3.w;
    sc[t] = acc * 0.25f;
  }

  // exact softmax (identical numerics to validated path)
  float mx[4], ex[4], sm[4], a[4];
#pragma unroll
  for (int t = 0; t < 4; ++t) mx[t] = sc[t];
#pragma unroll
  for (int off = 32; off >= 1; off >>= 1)
#pragma unroll
    for (int t = 0; t < 4; ++t) mx[t] = fmaxf(mx[t], __shfl_xor(mx[t], off));
#pragma unroll
  for (int t = 0; t < 4; ++t) { ex[t] = __expf(sc[t] - mx[t]); sm[t] = ex[t]; }
#pragma unroll
  for (int off = 32; off >= 1; off >>= 1)
#pragma unroll
    for (int t = 0; t < 4; ++t) sm[t] += __shfl_xor(sm[t], off);
#pragma unroll
  for (int t = 0; t < 4; ++t) { a[t] = ex[t] / sm[t]; als_t[wid][t][lane] = a[t]; }
  *(float4*)&als_k[wid][lane >> 4][lane & 15][0] = make_float4(a[0], a[1], a[2], a[3]);
  wave_sync();

  // stable top-16 by rank counting (value desc, index asc)
#pragma unroll
  for (int tt = 0; tt < 4; ++tt) {
    float myv = a[tt];
    int rank = 0;
    for (int j4 = 0; j4 < 64; j4 += 4) {
      float4 vj = *(const float4*)&als_t[wid][tt][j4];
      rank += (vj.x > myv) || (vj.x == myv && (j4 + 0) < lane);
      rank += (vj.y > myv) || (vj.y == myv && (j4 + 1) < lane);
      rank += (vj.z > myv) || (vj.z == myv && (j4 + 2) < lane);
      rank += (vj.w > myv) || (vj.w == myv && (j4 + 3) < lane);
    }
    if (rank < 16) {
      int n1 = (2 * hb + (tt >> 1)) * 64 + 2 * wb + (tt & 1);
      ti_out[((size_t)bh * 4096 + n1) * 16 + rank] = cand;
    }
  }

  // message: lane = (g, dd); group g covers candidates g*16..+15, all 4 t
  {
    const int g = lane >> 4, dd = lane & 15;
    float acc0 = 0.f, acc1 = 0.f, acc2 = 0.f, acc3 = 0.f;
#pragma unroll
    for (int k4 = 0; k4 < 16; k4 += 4) {
      int4 cv = *(const int4*)&cofs[wid][g * 16 + k4];
      float4 a0 = *(const float4*)&als_k[wid][g][k4 + 0][0];
      float4 a1 = *(const float4*)&als_k[wid][g][k4 + 1][0];
      float4 a2 = *(const float4*)&als_k[wid][g][k4 + 2][0];
      float4 a3 = *(const float4*)&als_k[wid][g][k4 + 3][0];
      float v0 = vt[cv.x + dd];
      float v1 = vt[cv.y + dd];
      float v2 = vt[cv.z + dd];
      float v3 = vt[cv.w + dd];
      acc0 += a0.x * v0; acc1 += a0.y * v0; acc2 += a0.z * v0; acc3 += a0.w * v0;
      acc0 += a1.x * v1; acc1 += a1.y * v1; acc2 += a1.z * v1; acc3 += a1.w * v1;
      acc0 += a2.x * v2; acc1 += a2.y * v2; acc2 += a2.z * v2; acc3 += a2.w * v2;
      acc0 += a3.x * v3; acc1 += a3.y * v3; acc2 += a3.z * v3; acc3 += a3.w * v3;
    }
    acc0 += __shfl_xor(acc0, 16); acc0 += __shfl_xor(acc0, 32);
    acc1 += __shfl_xor(acc1, 16); acc1 += __shfl_xor(acc1, 32);
    acc2 += __shfl_xor(acc2, 16); acc2 += __shfl_xor(acc2, 32);
    acc3 += __shfl_xor(acc3, 16); acc3 += __shfl_xor(acc3, 32);
    float msg = (g & 2) ? ((g & 1) ? acc3 : acc2) : ((g & 1) ? acc1 : acc0);
    int m = hb * 128 + (wb >> 3) * 32 + (g >> 1) * 16 + (wb & 7) * 2 + (g & 1);
    mc[(b * 4096 + m) * C + hD + dd] = msg;
  }
}

// ---------------- K3: fine attention, 2 units per wave (proven) -----------
__global__ __launch_bounds__(256) void attn_fine2(
    const float* __restrict__ qt, const float* __restrict__ kt,
    const float* __restrict__ vt, const int* __restrict__ tin,
    const float* __restrict__ mc, const float* __restrict__ weight,
    float* __restrict__ out)
{
  __shared__ alignas(16) float als_k[4][2][4][17][4]; // [wave][u][g][kk][t]
  __shared__ alignas(16) float qls[4][2][4][16];
  __shared__ alignas(16) int   cofs[4][2][64];

  const int lane = threadIdx.x & 63;
  const int wid  = threadIdx.x >> 6;
  const int wg = (blockIdx.x & 7) * 1024 + (blockIdx.x >> 3); // XCD swizzle
  const int p  = wg * 4 + wid;        // pair id [0, 32768)
  const int wb2 = p & 31;
  const int hb  = (p >> 5) & 63;
  const int h   = (p >> 11) & 7;
  const int b   = p >> 14;
  const int bh  = b * 8 + h;
  const int nA  = hb * 64 + wb2 * 2;  // unit A fine-n; B = nA+1
  const int hD  = h * 16;

  // q loads (both units)
  { int t = lane >> 4, dd = lane & 15;
    int rowq = (hb * 2 + (t >> 1)) * 128;
    qls[wid][0][t][dd] = qt[((size_t)bh * 16384 + rowq + wb2 * 4     + (t & 1)) * 16 + dd];
    qls[wid][1][t][dd] = qt[((size_t)bh * 16384 + rowq + wb2 * 4 + 2 + (t & 1)) * 16 + dd];
  }
  // parents -> candidate element offsets
  int off0A, off0B;
  { int kp = lane >> 2, c = lane & 3;
    int tA = tin[((size_t)bh * 4096 + nA    ) * 16 + kp];
    int tB = tin[((size_t)bh * 4096 + nA + 1) * 16 + kp];
    int candA = (2 * (tA >> 6) + (c >> 1)) * 128 + 2 * (tA & 63) + (c & 1);
    int candB = (2 * (tB >> 6) + (c >> 1)) * 128 + 2 * (tB & 63) + (c & 1);
    off0A = (bh * 16384 + candA) * 16;
    off0B = (bh * 16384 + candB) * 16;
    cofs[wid][0][lane] = off0A;
    cofs[wid][1][lane] = off0B;
  }
  wave_sync();

  // K gathers (two independent 64B rows in flight)
  float4 kA0, kA1, kA2, kA3, kB0, kB1, kB2, kB3;
  { const float4* kv = (const float4*)(kt + off0A); kA0 = kv[0]; kA1 = kv[1]; kA2 = kv[2]; kA3 = kv[3]; }
  { const float4* kv = (const float4*)(kt + off0B); kB0 = kv[0]; kB1 = kv[1]; kB2 = kv[2]; kB3 = kv[3]; }

  float ex0[4], ex1[4];
#pragma unroll
  for (int t = 0; t < 4; ++t) {
    { const float4* qv = (const float4*)qls[wid][0][t];
      float4 q0 = qv[0], q1 = qv[1], q2 = qv[2], q3 = qv[3];
      float acc = kA0.x*q0.x + kA0.y*q0.y + kA0.z*q0.z + kA0.w*q0.w
                + kA1.x*q1.x + kA1.y*q1.y + kA1.z*q1.z + kA1.w*q1.w
                + kA2.x*q2.x + kA2.y*q2.y + kA2.z*q2.z + kA2.w*q2.w
                + kA3.x*q3.x + kA3.y*q3.y + kA3.z*q3.z + kA3.w*q3.w;
      ex0[t] = __expf(acc * 0.25f); }
    { const float4* qv = (const float4*)qls[wid][1][t];
      float4 q0 = qv[0], q1 = qv[1], q2 = qv[2], q3 = qv[3];
      float acc = kB0.x*q0.x + kB0.y*q0.y + kB0.z*q0.z + kB0.w*q0.w
                + kB1.x*q1.x + kB1.y*q1.y + kB1.z*q1.z + kB1.w*q1.w
                + kB2.x*q2.x + kB2.y*q2.y + kB2.z*q2.z + kB2.w*q2.w
                + kB3.x*q3.x + kB3.y*q3.y + kB3.z*q3.z + kB3.w*q3.w;
      ex1[t] = __expf(acc * 0.25f); }
  }
  *(float4*)&als_k[wid][0][lane >> 4][lane & 15][0] = make_float4(ex0[0], ex0[1], ex0[2], ex0[3]);
  *(float4*)&als_k[wid][1][lane >> 4][lane & 15][0] = make_float4(ex1[0], ex1[1], ex1[2], ex1[3]);
  wave_sync();

  const int g = lane >> 4, dd = lane & 15;
  // prefetch coarse-message rows (latency hidden under trees + loop)
  float mcvA = mc[((size_t)b * 4096 + nA    ) * C + hD + dd];
  float mcvB = mc[((size_t)b * 4096 + nA + 1) * C + hD + dd];

  // denominators via interleaved shuffle trees (DS pipe, off VALU path)
  float smA[4], smB[4];
#pragma unroll
  for (int t = 0; t < 4; ++t) { smA[t] = ex0[t]; smB[t] = ex1[t]; }
#pragma unroll
  for (int off = 32; off >= 1; off >>= 1)
#pragma unroll
    for (int t = 0; t < 4; ++t) {
      smA[t] += __shfl_xor(smA[t], off);
      smB[t] += __shfl_xor(smB[t], off);
    }

  // message loops, A/B interleaved
  float aA0 = 0, aA1 = 0, aA2 = 0, aA3 = 0;
  float aB0 = 0, aB1 = 0, aB2 = 0, aB3 = 0;
#pragma unroll
  for (int k4 = 0; k4 < 16; k4 += 4) {
    int4 cvA = *(const int4*)&cofs[wid][0][g * 16 + k4];
    int4 cvB = *(const int4*)&cofs[wid][1][g * 16 + k4];
    float vA0 = vt[cvA.x + dd], vA1 = vt[cvA.y + dd];
    float vA2 = vt[cvA.z + dd], vA3 = vt[cvA.w + dd];
    float vB0 = vt[cvB.x + dd], vB1 = vt[cvB.y + dd];
    float vB2 = vt[cvB.z + dd], vB3 = vt[cvB.w + dd];
    float4 wA0 = *(const float4*)&als_k[wid][0][g][k4 + 0][0];
    float4 wA1 = *(const float4*)&als_k[wid][0][g][k4 + 1][0];
    float4 wA2 = *(const float4*)&als_k[wid][0][g][k4 + 2][0];
    float4 wA3 = *(const float4*)&als_k[wid][0][g][k4 + 3][0];
    float4 wB0 = *(const float4*)&als_k[wid][1][g][k4 + 0][0];
    float4 wB1 = *(const float4*)&als_k[wid][1][g][k4 + 1][0];
    float4 wB2 = *(const float4*)&als_k[wid][1][g][k4 + 2][0];
    float4 wB3 = *(const float4*)&als_k[wid][1][g][k4 + 3][0];
    aA0 += wA0.x * vA0; aA1 += wA0.y * vA0; aA2 += wA0.z * vA0; aA3 += wA0.w * vA0;
    aA0 += wA1.x * vA1; aA1 += wA1.y * vA1; aA2 += wA1.z * vA1; aA3 += wA1.w * vA1;
    aA0 += wA2.x * vA2; aA1 += wA2.y * vA2; aA2 += wA2.z * vA2; aA3 += wA2.w * vA2;
    aA0 += wA3.x * vA3; aA1 += wA3.y * vA3; aA2 += wA3.z * vA3; aA3 += wA3.w * vA3;
    aB0 += wB0.x * vB0; aB1 += wB0.y * vB0; aB2 += wB0.z * vB0; aB3 += wB0.w * vB0;
    aB0 += wB1.x * vB1; aB1 += wB1.y * vB1; aB2 += wB1.z * vB1; aB3 += wB1.w * vB1;
    aB0 += wB2.x * vB2; aB1 += wB2.y * vB2; aB2 += wB2.z * vB2; aB3 += wB2.w * vB2;
    aB0 += wB3.x * vB3; aB1 += wB3.y * vB3; aB2 += wB3.z * vB3; aB3 += wB3.w * vB3;
  }
  aA0 += __shfl_xor(aA0, 16); aA0 += __shfl_xor(aA0, 32);
  aA1 += __shfl_xor(aA1, 16); aA1 += __shfl_xor(aA1, 32);
  aA2 += __shfl_xor(aA2, 16); aA2 += __shfl_xor(aA2, 32);
  aA3 += __shfl_xor(aA3, 16); aA3 += __shfl_xor(aA3, 32);
  aB0 += __shfl_xor(aB0, 16); aB0 += __shfl_xor(aB0, 32);
  aB1 += __shfl_xor(aB1, 16); aB1 += __shfl_xor(aB1, 32);
  aB2 += __shfl_xor(aB2, 16); aB2 += __shfl_xor(aB2, 32);
  aB3 += __shfl_xor(aB3, 16); aB3 += __shfl_xor(aB3, 32);

  float msgA = (g & 2) ? ((g & 1) ? aA3 : aA2) : ((g & 1) ? aA1 : aA0);
  float msgB = (g & 2) ? ((g & 1) ? aB3 : aB2) : ((g & 1) ? aB1 : aB0);
  float smvA = (g & 2) ? ((g & 1) ? smA[3] : smA[2]) : ((g & 1) ? smA[1] : smA[0]);
  float smvB = (g & 2) ? ((g & 1) ? smB[3] : smB[2]) : ((g & 1) ? smB[1] : smB[0]);
  msgA /= smvA;
  msgB /= smvB;

  float w0 = weight[0], w1 = weight[1];
  float wm = fmaxf(w0, w1);
  float e0 = __expf(w0 - wm), e1 = __expf(w1 - wm);
  float inv = 1.0f / (e0 + e1);
  int rowq = (hb * 2 + (g >> 1)) * 128;
  out[((size_t)b * 16384 + rowq + wb2 * 4     + (g & 1)) * C + hD + dd] =
      (e0 * inv) * mcvA + (e1 * inv) * msgA;
  out[((size_t)b * 16384 + rowq + wb2 * 4 + 2 + (g & 1)) * C + hD + dd] =
      (e0 * inv) * mcvB + (e1 * inv) * msgB;
}

extern "C" void kernel_launch(void* const* d_in, const int* in_sizes, int n_in,
                              void* d_out, int out_size, void* d_ws, size_t ws_size,
                              hipStream_t stream) {
  const float* q_fine   = (const float*)d_in[0];
  const float* q_coarse = (const float*)d_in[1];
  const float* k_fine   = (const float*)d_in[2];
  const float* k_coarse = (const float*)d_in[3];
  const float* v_fine   = (const float*)d_in[4];
  const float* v_coarse = (const float*)d_in[5];
  const float* weight   = (const float*)d_in[6];
  const int*   topk_pos = (const int*)d_in[7];
  float* out = (float*)d_out;

  const int PF = 16384, PC = 4096;
  float* ws   = (float*)d_ws;
  float* qt_f = ws;                 // head-major [b][h][P][16]
  float* kt_f = qt_f + 2 * PF * C;
  float* vt_f = kt_f + 2 * PF * C;
  float* qt_c = vt_f + 2 * PF * C;
  float* kt_c = qt_c + 2 * PC * C;
  float* vt_c = kt_c + 2 * PC * C;
  float* mc   = vt_c + 2 * PC * C;          // 2*4096*C (permuted coarse message)
  int*   ti   = (int*)(mc + 2 * 4096 * C);  // head-major [b][h][4096][16]

  dim3 blk(256);
  // K1: coarse transpose (small, streaming)
  transpose_coarse<<<768, blk, 0, stream>>>(q_coarse, k_coarse, v_coarse,
                                            qt_c, kt_c, vt_c);
  // K2: coarse attn (plane-major, blocks 0..4095) + fine transpose backfill
  fused_mid<<<4096 + 3072, blk, 0, stream>>>(q_fine, k_fine, v_fine,
                                             qt_f, kt_f, vt_f,
                                             qt_c, kt_c, vt_c, topk_pos, mc, ti);
  // K3: fine attn, 2 units/wave -> 32768 pairs / 4 per block
  attn_fine2<<<8192, blk, 0, stream>>>(qt_f, kt_f, vt_f, ti, mc, weight, out);
}

// Round 10
// 91.870 us; speedup vs baseline: 1.4190x; 1.2047x over previous
//
#include <hip/hip_runtime.h>

#define C 128   // channels = nh*d = 8*16

// wave-local LDS fence: all attn LDS buffers are per-wave.
__device__ __forceinline__ void wave_sync() {
  __builtin_amdgcn_wave_barrier();
  asm volatile("s_waitcnt lgkmcnt(0)" ::: "memory");
  __builtin_amdgcn_wave_barrier();
}

// transpose one 32ch x 64pos tile of [b, C, P] -> head-major [b, h, P, 16]
// LDS: 32x65 floats = 8320 B (fits union with attn overlay, see fused_mid)
__device__ __forceinline__ void transpose_tile32(const float* __restrict__ in,
                                                 float* __restrict__ out, int P,
                                                 int tx, int chQ, int b,
                                                 float (*tile)[65]) {
  int posBase = tx * 64;
  int chBase  = chQ * 32;
  int tid = threadIdx.x;
  int lp = tid & 63;
  int lr = tid >> 6;
  const float* ip = in + (size_t)b * C * P;
  float* op = out + (size_t)b * C * P;
#pragma unroll
  for (int it = 0; it < 8; ++it) {
    int ch = lr + it * 4;   // 0..31
    tile[ch][lp] = ip[(size_t)(chBase + ch) * P + posBase + lp];
  }
  __syncthreads();
  int dd   = tid & 15;
  int hh2  = (tid >> 4) & 1;
  int prow = tid >> 5;      // 0..7
  int h = (chBase >> 4) + hh2;
#pragma unroll
  for (int it = 0; it < 8; ++it) {
    int pos = prow + it * 8;  // 0..63
    op[((size_t)h * P + posBase + pos) * 16 + dd] = tile[hh2 * 16 + dd][pos];
  }
}

// ---------------- K1: coarse transpose (1536 blocks) ----------------
__global__ __launch_bounds__(256) void transpose_coarse(
    const float* __restrict__ q, const float* __restrict__ k,
    const float* __restrict__ v, float* __restrict__ qo,
    float* __restrict__ ko, float* __restrict__ vo) {
  __shared__ alignas(16) float tile[32][65];
  int idx = blockIdx.x;          // 64 pos-tiles x 4 chQ x 3 sel x 2 b
  int tx = idx & 63;
  int ty = (idx >> 6) % 12;
  int tz = idx / 768;
  int sel = ty >> 2;
  const float* in = sel == 0 ? q : sel == 1 ? k : v;
  float* out      = sel == 0 ? qo : sel == 1 ? ko : vo;
  transpose_tile32(in, out, 4096, tx, ty & 3, tz, tile);
}

// ---------------- K2: coarse attn (blocks 0..4095, plane-major) + fine
//  transpose backfill (blocks 4096..10239). LDS union = 8320 B (small tile
//  + no als_t) -> 2x blocks/CU vs R9. Rank via ballot radix-select: finds
//  the 16th-largest EXACT softmax value by bit descent; downstream only
//  consumes the top-16 SET (fine level sums all 64 children symmetrically),
//  so ti slots use lane-compaction order.
__global__ __launch_bounds__(256) void fused_mid(
    const float* __restrict__ qf, const float* __restrict__ kf,
    const float* __restrict__ vf, float* __restrict__ qtf,
    float* __restrict__ ktf, float* __restrict__ vtf,
    const float* __restrict__ qt, const float* __restrict__ kt,
    const float* __restrict__ vt, const int* __restrict__ parents,
    float* __restrict__ mc, int* __restrict__ ti_out)
{
  __shared__ alignas(16) float lds[32 * 65];   // 2080 floats = 8320 B

  if (blockIdx.x >= 4096) {
    // ---- fine transpose: 256 pos-tiles x 4 chQ x 3 sel x 2 b = 6144 ----
    int idx = blockIdx.x - 4096;
    int tx = idx & 255;
    int ty = (idx >> 8) % 12;
    int tz = idx / 3072;
    int sel = ty >> 2;
    const float* in = sel == 0 ? qf : sel == 1 ? kf : vf;
    float* out      = sel == 0 ? qtf : sel == 1 ? ktf : vtf;
    transpose_tile32(in, out, 16384, tx, ty & 3, tz, (float (*)[65])lds);
    return;
  }

  // ---- coarse attention overlay: 1088 + 256 + 256 = 1600 floats <= 2080 --
  float (*als_k)[4][17][4] = (float (*)[4][17][4])lds;       // [wave][g][kk][t]
  float (*qls)[4][16]      = (float (*)[4][16])(lds + 1088); // [wave][t][dd]
  int   (*cofs)[64]        = (int (*)[64])    (lds + 1344);  // [wave][k]

  const int abid = blockIdx.x;
  const int lane = threadIdx.x & 63;
  const int wid  = threadIdx.x >> 6;
  const int wg = (abid & 7) * 512 + (abid >> 3);  // XCD-chunked swizzle
  const int u  = wg * 4 + wid;
  // plane-major decode: consecutive u = same (b,h) plane (L2-resident K/V)
  const int n  = u & 1023;
  const int bh = u >> 10;
  const int b  = bh >> 3;
  const int h  = bh & 7;
  const int hb = n >> 5;
  const int wb = n & 31;
  const int hD = h * 16;

  { int t = lane >> 4, dd = lane & 15;
    int pix = (hb * 2 + (t >> 1)) * 64 + (wb * 2 + (t & 1));
    qls[wid][t][dd] = qt[((size_t)bh * 4096 + pix) * 16 + dd]; }
  int cand, off0;
  { int kp = lane >> 2, c = lane & 3;
    int r  = parents[(size_t)b * 131072          + n * 128 + kp * 8 + h];
    int cc = parents[(size_t)b * 131072 + 262144 + n * 128 + kp * 8 + h];
    cand = (2 * r + (c >> 1)) * 64 + 2 * cc + (c & 1);
    off0 = (bh * 4096 + cand) * 16;
    cofs[wid][lane] = off0; }
  wave_sync();

  const float4* kv4 = (const float4*)(kt + off0);
  float4 k0 = kv4[0], k1 = kv4[1], k2 = kv4[2], k3 = kv4[3];
  float sc[4];
#pragma unroll
  for (int t = 0; t < 4; ++t) {
    const float4* qv = (const float4*)qls[wid][t];
    float4 q0 = qv[0], q1 = qv[1], q2 = qv[2], q3 = qv[3];
    float acc = k0.x*q0.x + k0.y*q0.y + k0.z*q0.z + k0.w*q0.w
              + k1.x*q1.x + k1.y*q1.y + k1.z*q1.z + k1.w*q1.w
              + k2.x*q2.x + k2.y*q2.y + k2.z*q2.z + k2.w*q2.w
              + k3.x*q3.x + k3.y*q3.y + k3.z*q3.z + k3.w*q3.w;
    sc[t] = acc * 0.25f;
  }

  // exact softmax (identical numerics to validated path)
  float mx[4], ex[4], sm[4], a[4];
#pragma unroll
  for (int t = 0; t < 4; ++t) mx[t] = sc[t];
#pragma unroll
  for (int off = 32; off >= 1; off >>= 1)
#pragma unroll
    for (int t = 0; t < 4; ++t) mx[t] = fmaxf(mx[t], __shfl_xor(mx[t], off));
#pragma unroll
  for (int t = 0; t < 4; ++t) { ex[t] = __expf(sc[t] - mx[t]); sm[t] = ex[t]; }
#pragma unroll
  for (int off = 32; off >= 1; off >>= 1)
#pragma unroll
    for (int t = 0; t < 4; ++t) sm[t] += __shfl_xor(sm[t], off);
#pragma unroll
  for (int t = 0; t < 4; ++t) a[t] = ex[t] / sm[t];
  *(float4*)&als_k[wid][lane >> 4][lane & 15][0] = make_float4(a[0], a[1], a[2], a[3]);

  // ---- top-16 SET via ballot radix-select on exact a (positive -> IEEE
  //  bits are uint-monotone). T = 16th-largest value; select u>T plus the
  //  lowest-index u==T lanes to fill 16 (matches reference value-desc,
  //  index-asc set). Slot = compaction index (any bijection is valid).
  {
    unsigned uu[4];
#pragma unroll
    for (int t = 0; t < 4; ++t) uu[t] = __float_as_uint(a[t]);
    unsigned T0 = 0, T1 = 0, T2 = 0, T3 = 0;
    for (int bit = 30; bit >= 0; --bit) {
      unsigned m = 1u << bit;
      unsigned c0 = T0 | m, c1 = T1 | m, c2 = T2 | m, c3 = T3 | m;
      if (__popcll(__ballot(uu[0] >= c0)) >= 16) T0 = c0;
      if (__popcll(__ballot(uu[1] >= c1)) >= 16) T1 = c1;
      if (__popcll(__ballot(uu[2] >= c2)) >= 16) T2 = c2;
      if (__popcll(__ballot(uu[3] >= c3)) >= 16) T3 = c3;
    }
    unsigned Tv[4] = {T0, T1, T2, T3};
    unsigned long long lower = (1ull << lane) - 1ull;
#pragma unroll
    for (int tt = 0; tt < 4; ++tt) {
      unsigned uv = uu[tt], T = Tv[tt];
      unsigned long long gt = __ballot(uv > T);
      unsigned long long eq = __ballot(uv == T);
      int ngt = __popcll(gt);
      bool sel = (uv > T) ||
                 ((uv == T) && (ngt + (int)__popcll(eq & lower) < 16));
      unsigned long long selm = __ballot(sel);
      int slot = __popcll(selm & lower);
      if (sel) {
        int n1 = (2 * hb + (tt >> 1)) * 64 + 2 * wb + (tt & 1);
        ti_out[((size_t)bh * 4096 + n1) * 16 + slot] = cand;
      }
    }
  }
  wave_sync();

  // message: lane = (g, dd); group g covers candidates g*16..+15, all 4 t
  {
    const int g = lane >> 4, dd = lane & 15;
    float acc0 = 0.f, acc1 = 0.f, acc2 = 0.f, acc3 = 0.f;
#pragma unroll
    for (int k4 = 0; k4 < 16; k4 += 4) {
      int4 cv = *(const int4*)&cofs[wid][g * 16 + k4];
      float4 a0 = *(const float4*)&als_k[wid][g][k4 + 0][0];
      float4 a1 = *(const float4*)&als_k[wid][g][k4 + 1][0];
      float4 a2 = *(const float4*)&als_k[wid][g][k4 + 2][0];
      float4 a3 = *(const float4*)&als_k[wid][g][k4 + 3][0];
      float v0 = vt[cv.x + dd];
      float v1 = vt[cv.y + dd];
      float v2 = vt[cv.z + dd];
      float v3 = vt[cv.w + dd];
      acc0 += a0.x * v0; acc1 += a0.y * v0; acc2 += a0.z * v0; acc3 += a0.w * v0;
      acc0 += a1.x * v1; acc1 += a1.y * v1; acc2 += a1.z * v1; acc3 += a1.w * v1;
      acc0 += a2.x * v2; acc1 += a2.y * v2; acc2 += a2.z * v2; acc3 += a2.w * v2;
      acc0 += a3.x * v3; acc1 += a3.y * v3; acc2 += a3.z * v3; acc3 += a3.w * v3;
    }
    acc0 += __shfl_xor(acc0, 16); acc0 += __shfl_xor(acc0, 32);
    acc1 += __shfl_xor(acc1, 16); acc1 += __shfl_xor(acc1, 32);
    acc2 += __shfl_xor(acc2, 16); acc2 += __shfl_xor(acc2, 32);
    acc3 += __shfl_xor(acc3, 16); acc3 += __shfl_xor(acc3, 32);
    float msg = (g & 2) ? ((g & 1) ? acc3 : acc2) : ((g & 1) ? acc1 : acc0);
    int m = hb * 128 + (wb >> 3) * 32 + (g >> 1) * 16 + (wb & 7) * 2 + (g & 1);
    mc[(b * 4096 + m) * C + hD + dd] = msg;
  }
}

// ---------------- K3: fine attention, 2 units per wave (proven) -----------
__global__ __launch_bounds__(256) void attn_fine2(
    const float* __restrict__ qt, const float* __restrict__ kt,
    const float* __restrict__ vt, const int* __restrict__ tin,
    const float* __restrict__ mc, const float* __restrict__ weight,
    float* __restrict__ out)
{
  __shared__ alignas(16) float als_k[4][2][4][17][4]; // [wave][u][g][kk][t]
  __shared__ alignas(16) float qls[4][2][4][16];
  __shared__ alignas(16) int   cofs[4][2][64];

  const int lane = threadIdx.x & 63;
  const int wid  = threadIdx.x >> 6;
  const int wg = (blockIdx.x & 7) * 1024 + (blockIdx.x >> 3); // XCD swizzle
  const int p  = wg * 4 + wid;        // pair id [0, 32768)
  const int wb2 = p & 31;
  const int hb  = (p >> 5) & 63;
  const int h   = (p >> 11) & 7;
  const int b   = p >> 14;
  const int bh  = b * 8 + h;
  const int nA  = hb * 64 + wb2 * 2;  // unit A fine-n; B = nA+1
  const int hD  = h * 16;

  // q loads (both units)
  { int t = lane >> 4, dd = lane & 15;
    int rowq = (hb * 2 + (t >> 1)) * 128;
    qls[wid][0][t][dd] = qt[((size_t)bh * 16384 + rowq + wb2 * 4     + (t & 1)) * 16 + dd];
    qls[wid][1][t][dd] = qt[((size_t)bh * 16384 + rowq + wb2 * 4 + 2 + (t & 1)) * 16 + dd];
  }
  // parents -> candidate element offsets
  int off0A, off0B;
  { int kp = lane >> 2, c = lane & 3;
    int tA = tin[((size_t)bh * 4096 + nA    ) * 16 + kp];
    int tB = tin[((size_t)bh * 4096 + nA + 1) * 16 + kp];
    int candA = (2 * (tA >> 6) + (c >> 1)) * 128 + 2 * (tA & 63) + (c & 1);
    int candB = (2 * (tB >> 6) + (c >> 1)) * 128 + 2 * (tB & 63) + (c & 1);
    off0A = (bh * 16384 + candA) * 16;
    off0B = (bh * 16384 + candB) * 16;
    cofs[wid][0][lane] = off0A;
    cofs[wid][1][lane] = off0B;
  }
  wave_sync();

  // K gathers (two independent 64B rows in flight)
  float4 kA0, kA1, kA2, kA3, kB0, kB1, kB2, kB3;
  { const float4* kv = (const float4*)(kt + off0A); kA0 = kv[0]; kA1 = kv[1]; kA2 = kv[2]; kA3 = kv[3]; }
  { const float4* kv = (const float4*)(kt + off0B); kB0 = kv[0]; kB1 = kv[1]; kB2 = kv[2]; kB3 = kv[3]; }

  float ex0[4], ex1[4];
#pragma unroll
  for (int t = 0; t < 4; ++t) {
    { const float4* qv = (const float4*)qls[wid][0][t];
      float4 q0 = qv[0], q1 = qv[1], q2 = qv[2], q3 = qv[3];
      float acc = kA0.x*q0.x + kA0.y*q0.y + kA0.z*q0.z + kA0.w*q0.w
                + kA1.x*q1.x + kA1.y*q1.y + kA1.z*q1.z + kA1.w*q1.w
                + kA2.x*q2.x + kA2.y*q2.y + kA2.z*q2.z + kA2.w*q2.w
                + kA3.x*q3.x + kA3.y*q3.y + kA3.z*q3.z + kA3.w*q3.w;
      ex0[t] = __expf(acc * 0.25f); }
    { const float4* qv = (const float4*)qls[wid][1][t];
      float4 q0 = qv[0], q1 = qv[1], q2 = qv[2], q3 = qv[3];
      float acc = kB0.x*q0.x + kB0.y*q0.y + kB0.z*q0.z + kB0.w*q0.w
                + kB1.x*q1.x + kB1.y*q1.y + kB1.z*q1.z + kB1.w*q1.w
                + kB2.x*q2.x + kB2.y*q2.y + kB2.z*q2.z + kB2.w*q2.w
                + kB3.x*q3.x + kB3.y*q3.y + kB3.z*q3.z + kB3.w*q3.w;
      ex1[t] = __expf(acc * 0.25f); }
  }
  *(float4*)&als_k[wid][0][lane >> 4][lane & 15][0] = make_float4(ex0[0], ex0[1], ex0[2], ex0[3]);
  *(float4*)&als_k[wid][1][lane >> 4][lane & 15][0] = make_float4(ex1[0], ex1[1], ex1[2], ex1[3]);
  wave_sync();

  const int g = lane >> 4, dd = lane & 15;
  // prefetch coarse-message rows (latency hidden under trees + loop)
  float mcvA = mc[((size_t)b * 4096 + nA    ) * C + hD + dd];
  float mcvB = mc[((size_t)b * 4096 + nA + 1) * C + hD + dd];

  // denominators via interleaved shuffle trees (DS pipe, off VALU path)
  float smA[4], smB[4];
#pragma unroll
  for (int t = 0; t < 4; ++t) { smA[t] = ex0[t]; smB[t] = ex1[t]; }
#pragma unroll
  for (int off = 32; off >= 1; off >>= 1)
#pragma unroll
    for (int t = 0; t < 4; ++t) {
      smA[t] += __shfl_xor(smA[t], off);
      smB[t] += __shfl_xor(smB[t], off);
    }

  // message loops, A/B interleaved
  float aA0 = 0, aA1 = 0, aA2 = 0, aA3 = 0;
  float aB0 = 0, aB1 = 0, aB2 = 0, aB3 = 0;
#pragma unroll
  for (int k4 = 0; k4 < 16; k4 += 4) {
    int4 cvA = *(const int4*)&cofs[wid][0][g * 16 + k4];
    int4 cvB = *(const int4*)&cofs[wid][1][g * 16 + k4];
    float vA0 = vt[cvA.x + dd], vA1 = vt[cvA.y + dd];
    float vA2 = vt[cvA.z + dd], vA3 = vt[cvA.w + dd];
    float vB0 = vt[cvB.x + dd], vB1 = vt[cvB.y + dd];
    float vB2 = vt[cvB.z + dd], vB3 = vt[cvB.w + dd];
    float4 wA0 = *(const float4*)&als_k[wid][0][g][k4 + 0][0];
    float4 wA1 = *(const float4*)&als_k[wid][0][g][k4 + 1][0];
    float4 wA2 = *(const float4*)&als_k[wid][0][g][k4 + 2][0];
    float4 wA3 = *(const float4*)&als_k[wid][0][g][k4 + 3][0];
    float4 wB0 = *(const float4*)&als_k[wid][1][g][k4 + 0][0];
    float4 wB1 = *(const float4*)&als_k[wid][1][g][k4 + 1][0];
    float4 wB2 = *(const float4*)&als_k[wid][1][g][k4 + 2][0];
    float4 wB3 = *(const float4*)&als_k[wid][1][g][k4 + 3][0];
    aA0 += wA0.x * vA0; aA1 += wA0.y * vA0; aA2 += wA0.z * vA0; aA3 += wA0.w * vA0;
    aA0 += wA1.x * vA1; aA1 += wA1.y * vA1; aA2 += wA1.z * vA1; aA3 += wA1.w * vA1;
    aA0 += wA2.x * vA2; aA1 += wA2.y * vA2; aA2 += wA2.z * vA2; aA3 += wA2.w * vA2;
    aA0 += wA3.x * vA3; aA1 += wA3.y * vA3; aA2 += wA3.z * vA3; aA3 += wA3.w * vA3;
    aB0 += wB0.x * vB0; aB1 += wB0.y * vB0; aB2 += wB0.z * vB0; aB3 += wB0.w * vB0;
    aB0 += wB1.x * vB1; aB1 += wB1.y * vB1; aB2 += wB1.z * vB1; aB3 += wB1.w * vB1;
    aB0 += wB2.x * vB2; aB1 += wB2.y * vB2; aB2 += wB2.z * vB2; aB3 += wB2.w * vB2;
    aB0 += wB3.x * vB3; aB1 += wB3.y * vB3; aB2 += wB3.z * vB3; aB3 += wB3.w * vB3;
  }
  aA0 += __shfl_xor(aA0, 16); aA0 += __shfl_xor(aA0, 32);
  aA1 += __shfl_xor(aA1, 16); aA1 += __shfl_xor(aA1, 32);
  aA2 += __shfl_xor(aA2, 16); aA2 += __shfl_xor(aA2, 32);
  aA3 += __shfl_xor(aA3, 16); aA3 += __shfl_xor(aA3, 32);
  aB0 += __shfl_xor(aB0, 16); aB0 += __shfl_xor(aB0, 32);
  aB1 += __shfl_xor(aB1, 16); aB1 += __shfl_xor(aB1, 32);
  aB2 += __shfl_xor(aB2, 16); aB2 += __shfl_xor(aB2, 32);
  aB3 += __shfl_xor(aB3, 16); aB3 += __shfl_xor(aB3, 32);

  float msgA = (g & 2) ? ((g & 1) ? aA3 : aA2) : ((g & 1) ? aA1 : aA0);
  float msgB = (g & 2) ? ((g & 1) ? aB3 : aB2) : ((g & 1) ? aB1 : aB0);
  float smvA = (g & 2) ? ((g & 1) ? smA[3] : smA[2]) : ((g & 1) ? smA[1] : smA[0]);
  float smvB = (g & 2) ? ((g & 1) ? smB[3] : smB[2]) : ((g & 1) ? smB[1] : smB[0]);
  msgA /= smvA;
  msgB /= smvB;

  float w0 = weight[0], w1 = weight[1];
  float wm = fmaxf(w0, w1);
  float e0 = __expf(w0 - wm), e1 = __expf(w1 - wm);
  float inv = 1.0f / (e0 + e1);
  int rowq = (hb * 2 + (g >> 1)) * 128;
  out[((size_t)b * 16384 + rowq + wb2 * 4     + (g & 1)) * C + hD + dd] =
      (e0 * inv) * mcvA + (e1 * inv) * msgA;
  out[((size_t)b * 16384 + rowq + wb2 * 4 + 2 + (g & 1)) * C + hD + dd] =
      (e0 * inv) * mcvB + (e1 * inv) * msgB;
}

extern "C" void kernel_launch(void* const* d_in, const int* in_sizes, int n_in,
                              void* d_out, int out_size, void* d_ws, size_t ws_size,
                              hipStream_t stream) {
  const float* q_fine   = (const float*)d_in[0];
  const float* q_coarse = (const float*)d_in[1];
  const float* k_fine   = (const float*)d_in[2];
  const float* k_coarse = (const float*)d_in[3];
  const float* v_fine   = (const float*)d_in[4];
  const float* v_coarse = (const float*)d_in[5];
  const float* weight   = (const float*)d_in[6];
  const int*   topk_pos = (const int*)d_in[7];
  float* out = (float*)d_out;

  const int PF = 16384, PC = 4096;
  float* ws   = (float*)d_ws;
  float* qt_f = ws;                 // head-major [b][h][P][16]
  float* kt_f = qt_f + 2 * PF * C;
  float* vt_f = kt_f + 2 * PF * C;
  float* qt_c = vt_f + 2 * PF * C;
  float* kt_c = qt_c + 2 * PC * C;
  float* vt_c = kt_c + 2 * PC * C;
  float* mc   = vt_c + 2 * PC * C;          // 2*4096*C (permuted coarse message)
  int*   ti   = (int*)(mc + 2 * 4096 * C);  // head-major [b][h][4096][16]

  dim3 blk(256);
  // K1: coarse transpose (small, streaming)
  transpose_coarse<<<1536, blk, 0, stream>>>(q_coarse, k_coarse, v_coarse,
                                             qt_c, kt_c, vt_c);
  // K2: coarse attn (plane-major, blocks 0..4095) + fine transpose backfill
  fused_mid<<<4096 + 6144, blk, 0, stream>>>(q_fine, k_fine, v_fine,
                                             qt_f, kt_f, vt_f,
                                             qt_c, kt_c, vt_c, topk_pos, mc, ti);
  // K3: fine attn, 2 units/wave -> 32768 pairs / 4 per block
  attn_fine2<<<8192, blk, 0, stream>>>(qt_f, kt_f, vt_f, ti, mc, weight, out);
}